// Round 5
// baseline (196.729 us; speedup 1.0000x reference)
//
#include <hip/hip_runtime.h>
#include <hip/hip_bf16.h>

#define B_ 2
#define S_ 2048
#define D_ 1024
#define H_ 16
#define HD_ 64

typedef __attribute__((ext_vector_type(8))) short short8;
typedef __attribute__((ext_vector_type(4))) float f32x4;
typedef __attribute__((ext_vector_type(16))) float f32x16;
typedef __attribute__((ext_vector_type(4))) unsigned short us4;

static __device__ __forceinline__ ushort f2bf(float x) {
  __hip_bfloat16 h = __float2bfloat16(x);
  return *reinterpret_cast<ushort*>(&h);
}

static __device__ __forceinline__ void gld_lds16(void* lds, const void* g) {
  __builtin_amdgcn_global_load_lds(
      (__attribute__((address_space(1))) void*)(g),
      (__attribute__((address_space(3))) void*)(lds), 16, 0, 0);
}

// ---------------- conversion kernels ----------------

__global__ __launch_bounds__(256) void cvt_bf16_vec(const float4* __restrict__ in,
                                                    ushort* __restrict__ out, int n4) {
  int i = blockIdx.x * blockDim.x + threadIdx.x;
  if (i < n4) {
    float4 v = in[i];
    ushort4 o;
    o.x = f2bf(v.x); o.y = f2bf(v.y); o.z = f2bf(v.z); o.w = f2bf(v.w);
    *reinterpret_cast<ushort4*>(out + (size_t)i * 4) = o;
  }
}

// in: [K][N] f32 row-major  ->  out: [N][K] bf16 row-major
__global__ __launch_bounds__(256) void transpose_cvt(const float* __restrict__ in,
                                                     ushort* __restrict__ out,
                                                     int K, int N) {
  __shared__ float tile[32][33];
  const int bn = blockIdx.x * 32, bk = blockIdx.y * 32;
  const int tx = threadIdx.x, ty = threadIdx.y;
  #pragma unroll
  for (int i = ty; i < 32; i += 8)
    tile[i][tx] = in[(size_t)(bk + i) * N + bn + tx];
  __syncthreads();
  #pragma unroll
  for (int i = ty; i < 32; i += 8)
    out[(size_t)(bn + i) * K + bk + tx] = f2bf(tile[tx][i]);
}

// ---------------- GEMM: C = A @ Bt^T + bias ----------------
template <bool OUT_BF16>
__global__ __launch_bounds__(256) void gemm_bt(const ushort* __restrict__ A,
                                               const ushort* __restrict__ Bt,
                                               const float* __restrict__ bias,
                                               ushort* __restrict__ Cb,
                                               float* __restrict__ Cf,
                                               int M, int N, int K) {
  __shared__ __align__(16) ushort As[128 * 32];
  __shared__ __align__(16) ushort Bs[128 * 32];
  const int tid = threadIdx.x;
  const int lane = tid & 63, wid = tid >> 6;
  const int wr = wid >> 1, wc = wid & 1;
  const int row0 = blockIdx.x * 128, col0 = blockIdx.y * 128;
  const int l15 = lane & 15, lhi = lane >> 4;

  f32x4 acc[4][4];
  #pragma unroll
  for (int i = 0; i < 4; ++i)
    #pragma unroll
    for (int j = 0; j < 4; ++j)
      acc[i][j] = f32x4{0.f, 0.f, 0.f, 0.f};

  const int sr = tid >> 2;
  const int scol = (tid & 3) * 8;

  for (int k0 = 0; k0 < K; k0 += 32) {
    gld_lds16(&As[(size_t)tid * 8],        &A[(size_t)(row0 + sr) * K + k0 + scol]);
    gld_lds16(&As[2048 + (size_t)tid * 8], &A[(size_t)(row0 + 64 + sr) * K + k0 + scol]);
    gld_lds16(&Bs[(size_t)tid * 8],        &Bt[(size_t)(col0 + sr) * K + k0 + scol]);
    gld_lds16(&Bs[2048 + (size_t)tid * 8], &Bt[(size_t)(col0 + 64 + sr) * K + k0 + scol]);
    __syncthreads();

    short8 af[4], bfr[4];
    #pragma unroll
    for (int mt = 0; mt < 4; ++mt)
      af[mt] = *(const short8*)&As[(wr * 64 + mt * 16 + l15) * 32 + lhi * 8];
    #pragma unroll
    for (int nt = 0; nt < 4; ++nt)
      bfr[nt] = *(const short8*)&Bs[(wc * 64 + nt * 16 + l15) * 32 + lhi * 8];
    #pragma unroll
    for (int mt = 0; mt < 4; ++mt)
      #pragma unroll
      for (int nt = 0; nt < 4; ++nt)
        acc[mt][nt] = __builtin_amdgcn_mfma_f32_16x16x32_bf16(af[mt], bfr[nt], acc[mt][nt], 0, 0, 0);
    __syncthreads();
  }

  const int orow = row0 + wr * 64;
  const int ocol = col0 + wc * 64 + l15;
  #pragma unroll
  for (int mt = 0; mt < 4; ++mt) {
    #pragma unroll
    for (int nt = 0; nt < 4; ++nt) {
      const int gc = ocol + nt * 16;
      const float bv = bias[gc];
      #pragma unroll
      for (int r = 0; r < 4; ++r) {
        const int gr = orow + mt * 16 + lhi * 4 + r;
        const float v = acc[mt][nt][r] + bv;
        if (OUT_BF16) Cb[(size_t)gr * N + gc] = f2bf(v);
        else          Cf[(size_t)gr * N + gc] = v;
      }
    }
  }
}

// ---------------- flash attention, 32x32 MFMA, KK=128 keys/iteration ----------------
// Same verified 64-key sub-tile layouts as round 4 (Ks/Vt indexed [buf][sub]),
// two sub-tiles processed per loop iteration sharing one barrier, one softmax
// reduction, one rescale, and fused 16-MFMA QK / PV clusters.  Defer-max (T13)
// skips the o/l rescale when the running max doesn't grow by > 8.
__global__ __launch_bounds__(256, 2) void flash_attn(const ushort* __restrict__ qkv,
                                                     const float* __restrict__ mask,
                                                     ushort* __restrict__ values) {
  __shared__ __align__(16) ushort Ks[2][2][64 * 64];
  __shared__ __align__(16) ushort Vt[2][2][64 * 64];

  const int tid = threadIdx.x;
  const int lane = tid & 63, wid = tid >> 6;
  const int l31 = lane & 31, lhalf = lane >> 5;
  const int qt = blockIdx.x, bh = blockIdx.y, b = bh >> 4, h = bh & 15;
  const size_t base = (size_t)b * S_ * 3072 + (size_t)h * 192;
  const int q = qt * 128 + wid * 32 + l31;

  // Q B-frags: qf[kd] = Q[q][kd*16 + lhalf*8 + 0..7]
  short8 qf[4];
  {
    const ushort* qrow = qkv + base + (size_t)q * 3072 + lhalf * 8;
    qf[0] = *(const short8*)(qrow);
    qf[1] = *(const short8*)(qrow + 16);
    qf[2] = *(const short8*)(qrow + 32);
    qf[3] = *(const short8*)(qrow + 48);
  }

  // K staging (per sub-tile of 64 rows): thread -> (srow 0..31, chunk sch 0..7)
  const int srow = tid >> 3, sch = tid & 7;
  const int hsr = (srow ^ (srow >> 3)) & 7;
  const int scs = sch ^ hsr;                 // rows 32..63 use scs^4
  // V staging: thread owns 4 keys x 4 d per sub-tile; column relabel sigma(kg)
  const int kg = tid & 15, d0 = (tid >> 4) * 4;
  const int skg = (kg & 12) | ((kg & 1) << 1) | ((kg >> 1) & 1);

  float m_run = -3.0e38f, l_run = 0.f;
  f32x16 o[2];
  #pragma unroll
  for (int dg = 0; dg < 2; ++dg)
    #pragma unroll
    for (int i = 0; i < 16; ++i) o[dg][i] = 0.f;

  const float* mrow = mask + ((size_t)b * S_ + q) * S_;
  const int NT2 = S_ / 128;
  int cur = 0;
  us4 vr[8];

  // ---- prologue: stage tile 0 (both sub-tiles) ----
  {
    #pragma unroll
    for (int s2 = 0; s2 < 2; ++s2) {
      const ushort* kgp = qkv + base + (size_t)(s2 * 64 + srow) * 3072 + 64;
      gld_lds16(&Ks[0][s2][tid * 8],        kgp + scs * 8);
      gld_lds16(&Ks[0][s2][2048 + tid * 8], kgp + (size_t)32 * 3072 + (scs ^ 4) * 8);
      #pragma unroll
      for (int kk = 0; kk < 4; ++kk)
        vr[s2 * 4 + kk] = *(const us4*)(qkv + base +
                           (size_t)(s2 * 64 + kg * 4 + kk) * 3072 + 128 + d0);
    }
    #pragma unroll
    for (int s2 = 0; s2 < 2; ++s2)
      #pragma unroll
      for (int dd = 0; dd < 4; ++dd) {
        const int d = d0 + dd;
        const int hd = (d ^ (d >> 3)) & 7;
        us4 w;
        w[0] = vr[s2 * 4 + 0][dd]; w[1] = vr[s2 * 4 + 1][dd];
        w[2] = vr[s2 * 4 + 2][dd]; w[3] = vr[s2 * 4 + 3][dd];
        *(us4*)&Vt[0][s2][d * 64 + (((skg >> 1) ^ hd) & 7) * 8 + (skg & 1) * 4] = w;
      }
    __syncthreads();
  }

  for (int t = 0; t < NT2; ++t) {
    const int nxt = cur ^ 1;
    const bool pre = (t + 1 < NT2);

    // ---- mask loads first (consumed after QK; L2-resident across heads) ----
    f32x4 mk[16];
    {
      const float* mp0 = mrow + (size_t)t * 128 + lhalf * 4;
      #pragma unroll
      for (int i = 0; i < 16; ++i)
        mk[i] = *(const f32x4*)(mp0 + (i >> 3) * 64 + ((i >> 2) & 1) * 32 + (i & 3) * 8);
    }

    // ---- issue next-tile K gld_lds + V register loads ----
    if (pre) {
      const size_t nb = base + (size_t)(t + 1) * 128 * 3072;
      #pragma unroll
      for (int s2 = 0; s2 < 2; ++s2) {
        const ushort* kgp = qkv + nb + (size_t)(s2 * 64 + srow) * 3072 + 64;
        gld_lds16(&Ks[nxt][s2][tid * 8],        kgp + scs * 8);
        gld_lds16(&Ks[nxt][s2][2048 + tid * 8], kgp + (size_t)32 * 3072 + (scs ^ 4) * 8);
        #pragma unroll
        for (int kk = 0; kk < 4; ++kk)
          vr[s2 * 4 + kk] = *(const us4*)(qkv + nb +
                             (size_t)(s2 * 64 + kg * 4 + kk) * 3072 + 128 + d0);
      }
    }

    // ---- QK^T: 16 MFMA over 128 keys ----
    f32x16 sc[4];
    __builtin_amdgcn_s_setprio(1);
    #pragma unroll
    for (int s2 = 0; s2 < 2; ++s2)
      #pragma unroll
      for (int g = 0; g < 2; ++g) {
        const int row = g * 32 + l31;
        const int hk = (row ^ (row >> 3)) & 7;
        const ushort* kp = &Ks[cur][s2][row * 64];
        f32x16 s;
        #pragma unroll
        for (int i = 0; i < 16; ++i) s[i] = 0.f;
        #pragma unroll
        for (int kd = 0; kd < 4; ++kd) {
          short8 kf = *(const short8*)&kp[(((kd * 2 + lhalf) ^ hk) & 7) * 8];
          s = __builtin_amdgcn_mfma_f32_32x32x16_bf16(kf, qf[kd], s, 0, 0, 0);
        }
        sc[s2 * 2 + g] = s;
      }
    __builtin_amdgcn_s_setprio(0);

    // ---- scale + mask ----
    #pragma unroll
    for (int c4 = 0; c4 < 4; ++c4)
      #pragma unroll
      for (int r = 0; r < 16; ++r)
        sc[c4][r] = sc[c4][r] * 0.125f + mk[(c4 >> 1) * 8 + (c4 & 1) * 4 + (r >> 2)][r & 3];

    // ---- softmax over 128 keys (per-lane q; 1 shfl; defer-max THR=8) ----
    float mx = sc[0][0];
    #pragma unroll
    for (int c4 = 0; c4 < 4; ++c4)
      #pragma unroll
      for (int r = 0; r < 16; ++r) mx = fmaxf(mx, sc[c4][r]);
    mx = fmaxf(mx, __shfl_xor(mx, 32));
    if (__any(mx > m_run + 8.0f)) {
      const float mnew = fmaxf(m_run, mx);
      const float alpha = __expf(m_run - mnew);
      m_run = mnew;
      l_run *= alpha;
      #pragma unroll
      for (int dg = 0; dg < 2; ++dg)
        #pragma unroll
        for (int i = 0; i < 16; ++i) o[dg][i] *= alpha;
    }
    float ps = 0.f;
    #pragma unroll
    for (int c4 = 0; c4 < 4; ++c4)
      #pragma unroll
      for (int r = 0; r < 16; ++r) {
        const float p = __expf(sc[c4][r] - m_run);
        sc[c4][r] = p;
        ps += p;
      }
    ps += __shfl_xor(ps, 32);
    l_run += ps;

    // ---- P fragments: pi-permuted k-axis, pure in-register ----
    short8 pf[8];
    #pragma unroll
    for (int ks = 0; ks < 8; ++ks) {
      const int sub = ks >> 2, k2 = ks & 3;
      #pragma unroll
      for (int j = 0; j < 8; ++j)
        pf[ks][j] = (short)f2bf(sc[sub * 2 + (k2 >> 1)][8 * (k2 & 1) + j]);
    }

    // ---- PV: 16 MFMA ----
    __builtin_amdgcn_s_setprio(1);
    #pragma unroll
    for (int dg = 0; dg < 2; ++dg) {
      const int d = dg * 32 + l31;
      const int hv = (d ^ (d >> 3)) & 7;
      #pragma unroll
      for (int ks = 0; ks < 8; ++ks) {
        const int sub = ks >> 2, kl = ks & 3;
        const ushort* vp = &Vt[cur][sub][d * 64];
        short8 vf = *(const short8*)&vp[(((kl * 2 + lhalf) ^ hv) & 7) * 8];
        o[dg] = __builtin_amdgcn_mfma_f32_32x32x16_bf16(vf, pf[ks], o[dg], 0, 0, 0);
      }
    }
    __builtin_amdgcn_s_setprio(0);

    // ---- late: V register-transpose into Vt[nxt] ----
    if (pre) {
      #pragma unroll
      for (int s2 = 0; s2 < 2; ++s2)
        #pragma unroll
        for (int dd = 0; dd < 4; ++dd) {
          const int d = d0 + dd;
          const int hd = (d ^ (d >> 3)) & 7;
          us4 w;
          w[0] = vr[s2 * 4 + 0][dd]; w[1] = vr[s2 * 4 + 1][dd];
          w[2] = vr[s2 * 4 + 2][dd]; w[3] = vr[s2 * 4 + 3][dd];
          *(us4*)&Vt[nxt][s2][d * 64 + (((skg >> 1) ^ hd) & 7) * 8 + (skg & 1) * 4] = w;
        }
    }
    __syncthreads();
    cur = nxt;
  }

  // ---- epilogue: O^T/l -> values[bh][q][d] ----
  const float inv = 1.0f / l_run;
  ushort* vout = values + ((size_t)bh * S_ + q) * 64;
  #pragma unroll
  for (int dg = 0; dg < 2; ++dg)
    #pragma unroll
    for (int quad = 0; quad < 4; ++quad) {
      us4 w;
      #pragma unroll
      for (int r = 0; r < 4; ++r) w[r] = f2bf(o[dg][quad * 4 + r] * inv);
      *(us4*)(vout + dg * 32 + quad * 8 + lhalf * 4) = w;
    }
}

// ---------------- launch ----------------

extern "C" void kernel_launch(void* const* d_in, const int* in_sizes, int n_in,
                              void* d_out, int out_size, void* d_ws, size_t ws_size,
                              hipStream_t stream) {
  const float* x    = (const float*)d_in[0];
  const float* mask = (const float*)d_in[1];
  const float* Wqkv = (const float*)d_in[2];
  const float* bqkv = (const float*)d_in[3];
  const float* Wo   = (const float*)d_in[4];
  const float* bo   = (const float*)d_in[5];
  float* out = (float*)d_out;

  char* ws = (char*)d_ws;
  ushort* xbf    = (ushort*)(ws + 0);
  ushort* vals   = (ushort*)(ws + 0);
  ushort* wqkvT  = (ushort*)(ws + 8388608);
  ushort* woT    = (ushort*)(ws + 14680064);
  ushort* qkv    = (ushort*)(ws + 16777216);

  cvt_bf16_vec<<<4096, 256, 0, stream>>>((const float4*)x, xbf, (B_ * S_ * D_) / 4);
  transpose_cvt<<<dim3(3 * D_ / 32, D_ / 32), dim3(32, 8), 0, stream>>>(Wqkv, wqkvT, D_, 3 * D_);
  transpose_cvt<<<dim3(D_ / 32, D_ / 32), dim3(32, 8), 0, stream>>>(Wo, woT, D_, D_);
  gemm_bt<true><<<dim3((B_ * S_) / 128, (3 * D_) / 128), 256, 0, stream>>>(
      xbf, wqkvT, bqkv, qkv, nullptr, B_ * S_, 3 * D_, D_);
  flash_attn<<<dim3(S_ / 128, B_ * H_), 256, 0, stream>>>(qkv, mask, vals);
  gemm_bt<false><<<dim3((B_ * S_) / 128, D_ / 128), 256, 0, stream>>>(
      vals, woT, bo, nullptr, out, B_ * S_, D_, D_);
}